// Round 3
// baseline (22746.635 us; speedup 1.0000x reference)
//
#include <hip/hip_runtime.h>
#include <hip/hip_cooperative_groups.h>

namespace cg = cooperative_groups;

#define N_      800
#define C_      64
#define TRS_    40
#define SPT_    10
#define T_      400
#define HIST_   520           // 120 history + 400 produced rows (time-major)
#define KPL     13            // edges per lane: 13*64 = 832 >= 800
#define SENT    0x7FC00BADu   // qNaN sentinel for "not yet written"
#define WSLOTS  17            // 16 readable rows + 1 write slot -> no intra-step conflict

#define A_F     (-0.5f)
#define OMEGA_F (10.0f)
#define G_F     (500.0f)
#define KGI_F   (5.0f)
#define DT_F    (1e-4f)

#define ALD(p)    __hip_atomic_load((p), __ATOMIC_RELAXED, __HIP_MEMORY_SCOPE_AGENT)
#define AST(p,v)  __hip_atomic_store((p), (v), __ATOMIC_RELAXED, __HIP_MEMORY_SCOPE_AGENT)

// ---------------- prelude kernels (unchanged, proven) ----------------

__global__ void k_sumsq(const float* __restrict__ sc, float* __restrict__ sumsq) {
    __shared__ float sh[4];
    int tid = threadIdx.x;
    int idx = blockIdx.x * 256 + tid;
    float s = 0.f;
    for (int i = idx; i < N_ * N_; i += 256 * 256) { float v = sc[i]; s += v * v; }
    #pragma unroll
    for (int o = 1; o < 64; o <<= 1) s += __shfl_xor(s, o, 64);
    if ((tid & 63) == 0) sh[tid >> 6] = s;
    __syncthreads();
    if (tid == 0) atomicAdd(sumsq, sh[0] + sh[1] + sh[2] + sh[3]);
}

__global__ void k_detect(const int* __restrict__ dw, int* __restrict__ flag) {
    __shared__ int sh[4];
    int tid = threadIdx.x;
    int v = 0;
    for (int idx = 2 * tid + 1; idx < 800; idx += 512) v |= dw[idx];
    #pragma unroll
    for (int o = 1; o < 64; o <<= 1) v |= __shfl_xor(v, o, 64);
    if ((tid & 63) == 0) sh[tid >> 6] = v;
    __syncthreads();
    if (tid == 0) flag[0] = ((sh[0] | sh[1] | sh[2] | sh[3]) == 0) ? 1 : 0; // 1 => int64
}

// time-major state: xg[(120+time)*800 + j] = x_j(time); rows 0..119 from hE, rest SENT
__global__ void k_init(const float* __restrict__ hE, unsigned int* __restrict__ xg) {
    int idx = blockIdx.x * 256 + threadIdx.x;
    if (idx >= HIST_ * N_) return;
    int s = idx / N_, j = idx - s * N_;
    unsigned int v = (s < 120) ? __float_as_uint(hE[j * 120 + (119 - s)]) : SENT;
    xg[idx] = v;
}

// ---------------- main persistent kernel ----------------
// 100 blocks x 512 threads; wave (b,w) owns row i = b*8+w.
// Delay classes: d<=5   scattered ALD poll (only d=0 is zero-slack)
//                6..21  gather from 17-slot rolling LDS window W (row t-6 staged
//                       each step with 6-step slack; 17th slot kills all
//                       intra-step write/read conflicts -> ONE barrier/step)
//                >=22   scatter-forward into per-wave LDS ring, batched every 16
//                       steps from W, phase-staggered per block (no global bursts)

__global__ void __launch_bounds__(512, 1) k_main(
    const float* __restrict__ sc, const int* __restrict__ dw,
    const float* __restrict__ hx, const float* __restrict__ external,
    const float* __restrict__ noise, const float* __restrict__ lm,
    const float* __restrict__ sumsq, const int* __restrict__ flag,
    unsigned int* __restrict__ xg, float* __restrict__ xtr, float* __restrict__ out)
{
    cg::grid_group grid = cg::this_grid();
    __shared__ float W[WSLOTS * N_];  // row s lives at slot (s+170)%17
    __shared__ float ring[8][128];    // per-wave far-coupling ring

    const int tid  = threadIdx.x;
    const int lane = tid & 63;
    const int wid  = tid >> 6;
    const int i    = blockIdx.x * 8 + wid;
    const int p    = blockIdx.x & 15;          // far-batch phase stagger

    const float inv_norm = 1.0f / sqrtf(*sumsq);
    const int is64 = *flag;

    // per-lane edge metadata
    float w_[KPL]; int d_[KPL]; int jj_[KPL];
    float rsum = 0.f;
    #pragma unroll
    for (int k = 0; k < KPL; ++k) {
        int j = k * 64 + lane;
        bool valid = (j < N_);
        jj_[k] = valid ? j : 0;
        int base = i * N_ + jj_[k];
        float wv = valid ? fabsf(sc[base]) * inv_norm : 0.f;
        d_[k] = valid ? dw[is64 ? (base << 1) : base] : 0;
        w_[k] = wv;
        rsum += wv;
    }
    #pragma unroll
    for (int o = 1; o < 64; o <<= 1) rsum += __shfl_xor(rsum, o, 64);

    // zero own ring (wave-private)
    ring[wid][lane] = 0.f;
    ring[wid][64 + lane] = 0.f;

    // ---- prologue A: far-history scatter, sources s in [-120, p-23] ----
    // (batch at t=p covers [p-22, p-7]; later batches contiguous)
    #pragma unroll 1
    for (int s = -120; s <= p - 23; ++s) {
        const unsigned int* row = xg + (120 + s) * N_;   // history, never SENT
        #pragma unroll
        for (int k = 0; k < KPL; ++k) {
            if (d_[k] >= 22 && w_[k] != 0.f) {
                int tt = s + 1 + d_[k];
                if (tt >= 0)
                    atomicAdd(&ring[wid][tt & 127],
                              w_[k] * __uint_as_float(row[jj_[k]]));
            }
        }
    }

    // ---- prologue B: pre-stage W rows s = -22..-7 (xg rows 98..113) ----
    for (int r = 0; r < 16; ++r) {
        int s = -22 + r;
        int slot = (s + 170) % WSLOTS;
        for (int idx = tid; idx < N_; idx += 512)
            W[slot * N_ + idx] = __uint_as_float(xg[(120 + s) * N_ + idx]);
    }

    float x = hx[2 * i], y = hx[2 * i + 1];
    __syncthreads();

    #pragma unroll 1
    for (int t = 0; t < T_; ++t) {
        // ---- 1. issue stage loads for row t-6 (6-step slack, straight ALD) ----
        const unsigned int* Sr = xg + (114 + t) * N_;
        unsigned int sv0 = ALD(&Sr[tid]);
        unsigned int sv1 = (tid < N_ - 512) ? ALD(&Sr[tid + 512]) : 0u;

        // ---- 2. issue first poll attempt (d<=5) ----
        unsigned int vv[KPL];
        #pragma unroll
        for (int k = 0; k < KPL; ++k) {
            bool act = (d_[k] <= 5) && (w_[k] != 0.f);
            vv[k] = act ? ALD(&xg[(119 + t - d_[k]) * N_ + jj_[k]]) : 0u;
        }

        // ---- 3. far batch every 16 steps (phase-staggered), sources [t-22, t-7] ----
        if (((t - p) & 15) == 0) {
            #pragma unroll 1
            for (int r = 0; r < 16; ++r) {
                int s = t - 22 + r;
                const float* Wr = W + ((s + 170) % WSLOTS) * N_;
                #pragma unroll
                for (int k = 0; k < KPL; ++k) {
                    if (d_[k] >= 22 && w_[k] != 0.f)
                        atomicAdd(&ring[wid][(s + 1 + d_[k]) & 127],
                                  w_[k] * Wr[jj_[k]]);
                }
            }
        }

        // ---- 4. mid gather from W (6 <= d <= 21 -> rows [t-22, t-7]) ----
        float acc = 0.f;
        #pragma unroll
        for (int k = 0; k < KPL; ++k) {
            int dv = d_[k];
            int dd = dv < 6 ? 6 : (dv > 21 ? 21 : dv);
            float wv = ((dv >= 6) & (dv <= 21)) ? w_[k] : 0.f;
            int slot = (t - 1 - dd + 170) % WSLOTS;
            acc += wv * W[slot * N_ + jj_[k]];
        }

        // ---- 5. poll retry (only d=0 truly zero-slack) ----
        int g = 0;
        while (true) {
            int pend = 0;
            #pragma unroll
            for (int k = 0; k < KPL; ++k) pend |= (vv[k] == SENT) ? 1 : 0;
            if (!__any(pend)) break;
            if (++g > 100000000) break;                 // safety valve
            #pragma unroll
            for (int k = 0; k < KPL; ++k)
                if (vv[k] == SENT)
                    vv[k] = ALD(&xg[(119 + t - d_[k]) * N_ + jj_[k]]);
        }
        #pragma unroll
        for (int k = 0; k < KPL; ++k)
            acc += ((d_[k] <= 5) ? w_[k] : 0.f) * __uint_as_float(vv[k]);
        #pragma unroll
        for (int o = 1; o < 64; o <<= 1) acc += __shfl_xor(acc, o, 64);

        float led = acc + ring[wid][t & 127];
        if (lane == 0) ring[wid][t & 127] = 0.f;        // reused at t+128, safe

        // ---- 6. integrate / publish ----
        int tr = (t * 205) >> 11;                       // t/10 for t<400
        int sp = t - tr * 10;
        float u  = external[(i * SPT_ + sp) * TRS_ + tr];
        float n0 = noise[(t * N_ + i) * 2 + 0];
        float n1 = noise[(t * N_ + i) * 2 + 1];

        float r2 = x * x + y * y;
        float dx = (A_F - r2) * x - OMEGA_F * y + G_F * (led - rsum * x) + KGI_F * u;
        float dy = (A_F - r2) * y + OMEGA_F * x;
        x = x + DT_F * dx + n0;
        y = y + DT_F * dy + n1;

        if (lane == 0) {
            AST(&xg[(120 + t) * N_ + i], __float_as_uint(x));
            if (sp == SPT_ - 1) xtr[tr * N_ + i] = x;
        }

        // ---- 7. finish staging: rare retry, write W slot (17th slot: no reader) ----
        {
            int gg = 0;
            while (sv0 == SENT) { sv0 = ALD(&Sr[tid]); if (++gg > 100000000) break; }
            if (tid < N_ - 512) {
                gg = 0;
                while (sv1 == SENT) { sv1 = ALD(&Sr[tid + 512]); if (++gg > 100000000) break; }
            }
            int ss = (t - 6 + 170) % WSLOTS;
            W[ss * N_ + tid] = __uint_as_float(sv0);
            if (tid < N_ - 512) W[ss * N_ + tid + 512] = __uint_as_float(sv1);
        }
        __syncthreads();   // staged row visible to next step's readers
    }

    grid.sync();   // make xtr visible for the epilogue

    // epilogue: out[c*TRS + tr] = 5 * dot(xtr[tr,:], lm[c,:]) - 2
    for (int o = i; o < C_ * TRS_; o += 800) {
        int c = o / TRS_, tr = o - c * TRS_;
        float s = 0.f;
        #pragma unroll
        for (int k = 0; k < KPL; ++k) {
            int n = k * 64 + lane;
            if (n < N_) s += xtr[tr * N_ + n] * lm[c * N_ + n];
        }
        #pragma unroll
        for (int o2 = 1; o2 < 64; o2 <<= 1) s += __shfl_xor(s, o2, 64);
        if (lane == 0) out[o] = 5.0f * s - 2.0f;
    }
}

// ---------------- launch ----------------

extern "C" void kernel_launch(void* const* d_in, const int* in_sizes, int n_in,
                              void* d_out, int out_size, void* d_ws, size_t ws_size,
                              hipStream_t stream) {
    const float* external = (const float*)d_in[0];
    const float* hx       = (const float*)d_in[1];
    const float* hE       = (const float*)d_in[2];
    const float* sc       = (const float*)d_in[3];
    const float* lm       = (const float*)d_in[4];
    const float* noise    = (const float*)d_in[5];
    const int*   delays   = (const int*)  d_in[6];
    float* out = (float*)d_out;

    float*        sumsq = (float*)d_ws;                    // ws[0]
    int*          flag  = (int*)d_ws + 1;                  // ws[1]
    unsigned int* xg    = (unsigned int*)d_ws + 64;        // 520*800 words, time-major
    float*        xtr   = (float*)(xg + HIST_ * N_);       // 40*800 floats

    hipMemsetAsync(d_ws, 0, 8, stream);
    k_sumsq<<<256, 256, 0, stream>>>(sc, sumsq);
    k_detect<<<1, 256, 0, stream>>>(delays, flag);
    k_init<<<(HIST_ * N_ + 255) / 256, 256, 0, stream>>>(hE, xg);

    void* args[] = { (void*)&sc, (void*)&delays, (void*)&hx, (void*)&external,
                     (void*)&noise, (void*)&lm, (void*)&sumsq, (void*)&flag,
                     (void*)&xg, (void*)&xtr, (void*)&out };
    hipLaunchCooperativeKernel((const void*)k_main, dim3(100), dim3(512), args, 0, stream);
}

// Round 4
// 4668.678 us; speedup vs baseline: 4.8722x; 4.8722x over previous
//
#include <hip/hip_runtime.h>
#include <hip/hip_cooperative_groups.h>

namespace cg = cooperative_groups;

#define N_      800
#define C_      64
#define TRS_    40
#define SPT_    10
#define T_      400
#define HIST_   520           // 120 history + 400 produced rows (time-major)
#define KPL     13            // edges per lane: 13*64 = 832 >= 800
#define SENT    0x7FC00BADu   // qNaN sentinel for "not yet written"
#define NEAR_D  16            // d < 16: per-step ALD poll; d >= 16: LDS ring scatter

#define A_F     (-0.5f)
#define OMEGA_F (10.0f)
#define G_F     (500.0f)
#define KGI_F   (5.0f)
#define DT_F    (1e-4f)

#define ALD(p)    __hip_atomic_load((p), __ATOMIC_RELAXED, __HIP_MEMORY_SCOPE_AGENT)
#define AST(p,v)  __hip_atomic_store((p), (v), __ATOMIC_RELAXED, __HIP_MEMORY_SCOPE_AGENT)

// ---------------- prelude kernels (unchanged, proven) ----------------

__global__ void k_sumsq(const float* __restrict__ sc, float* __restrict__ sumsq) {
    __shared__ float sh[4];
    int tid = threadIdx.x;
    int idx = blockIdx.x * 256 + tid;
    float s = 0.f;
    for (int i = idx; i < N_ * N_; i += 256 * 256) { float v = sc[i]; s += v * v; }
    #pragma unroll
    for (int o = 1; o < 64; o <<= 1) s += __shfl_xor(s, o, 64);
    if ((tid & 63) == 0) sh[tid >> 6] = s;
    __syncthreads();
    if (tid == 0) atomicAdd(sumsq, sh[0] + sh[1] + sh[2] + sh[3]);
}

__global__ void k_detect(const int* __restrict__ dw, int* __restrict__ flag) {
    __shared__ int sh[4];
    int tid = threadIdx.x;
    int v = 0;
    for (int idx = 2 * tid + 1; idx < 800; idx += 512) v |= dw[idx];
    #pragma unroll
    for (int o = 1; o < 64; o <<= 1) v |= __shfl_xor(v, o, 64);
    if ((tid & 63) == 0) sh[tid >> 6] = v;
    __syncthreads();
    if (tid == 0) flag[0] = ((sh[0] | sh[1] | sh[2] | sh[3]) == 0) ? 1 : 0; // 1 => int64
}

// time-major state: xg[(120+time)*800 + j] = x_j(time); rows 0..119 from hE, rest SENT
__global__ void k_init(const float* __restrict__ hE, unsigned int* __restrict__ xg) {
    int idx = blockIdx.x * 256 + threadIdx.x;
    if (idx >= HIST_ * N_) return;
    int s = idx / N_, j = idx - s * N_;
    unsigned int v = (s < 120) ? __float_as_uint(hE[j * 120 + (119 - s)]) : SENT;
    xg[idx] = v;
}

// ---------------- main persistent kernel ----------------
// R0's elastic structure (NO barriers in main loop, per-wave autonomy) with the
// far path (d>=16) moved into a wave-private LDS ring:
//   every 16 steps, read the 16 newly-complete rows [t-17, t-2] (coalesced,
//   cached, sentinel-retry) and scatter w*x into ring slot (s+1+d)&127.
//   Per step the far coupling is ONE broadcast ds_read.
// Near path (d<16): byte-for-byte R0's scattered ALD poll.

__global__ void __launch_bounds__(512, 1) k_main(
    const float* __restrict__ sc, const int* __restrict__ dw,
    const float* __restrict__ hx, const float* __restrict__ external,
    const float* __restrict__ noise, const float* __restrict__ lm,
    const float* __restrict__ sumsq, const int* __restrict__ flag,
    unsigned int* __restrict__ xg, float* __restrict__ xtr, float* __restrict__ out)
{
    cg::grid_group grid = cg::this_grid();
    __shared__ float ring[8][128];    // wave-private far-coupling rings

    const int lane = threadIdx.x & 63;
    const int wid  = threadIdx.x >> 6;
    const int i    = blockIdx.x * 8 + wid;

    const float inv_norm = 1.0f / sqrtf(*sumsq);
    const int is64 = *flag;

    // per-lane edge metadata: j = k*64+lane
    float wn[KPL], wf[KPL]; int an[KPL], df[KPL], jj_[KPL];
    float rsum = 0.f;
    #pragma unroll
    for (int k = 0; k < KPL; ++k) {
        int j = k * 64 + lane;
        bool valid = (j < N_);
        jj_[k] = valid ? j : 0;
        int base = i * N_ + jj_[k];
        float wv = valid ? fabsf(sc[base]) * inv_norm : 0.f;
        int dv = valid ? dw[is64 ? (base << 1) : base] : 0;
        rsum += wv;
        bool nearc = valid && (dv < NEAR_D);
        wn[k] = nearc ? wv : 0.f;
        wf[k] = (valid && dv >= NEAR_D) ? wv : 0.f;
        an[k] = (119 - dv) * N_ + jj_[k];   // + t*N_ -> value x_j(t-1-d)
        df[k] = 1 + dv;                     // ring target offset from source step
    }
    #pragma unroll
    for (int o = 1; o < 64; o <<= 1) rsum += __shfl_xor(rsum, o, 64);

    // zero own ring (wave-private; same-wave LDS ops are in order, no barrier)
    ring[wid][lane] = 0.f;
    ring[wid][64 + lane] = 0.f;

    // ---- prologue: scatter initial history, sources s in [-120, -18] ----
    // (sources [-17, -2] are covered by the t=0 batch, [-1, ...] by t=16, etc.)
    #pragma unroll 1
    for (int s = -120; s <= -18; ++s) {
        const unsigned int* row = xg + (120 + s) * N_;   // history, never SENT
        #pragma unroll
        for (int k = 0; k < KPL; ++k) {
            if (wf[k] != 0.f) {
                int tt = s + df[k];
                if (tt >= 0)
                    atomicAdd(&ring[wid][tt & 127],
                              wf[k] * __uint_as_float(row[jj_[k]]));
            }
        }
    }

    float x = hx[2 * i], y = hx[2 * i + 1];

    #pragma unroll 1
    for (int t = 0; t < T_; ++t) {
        // ---- far batch every 16 steps: sources [t-17, t-2], >=2 steps slack ----
        if ((t & 15) == 0) {
            #pragma unroll 1
            for (int r = 0; r < 16; ++r) {
                int s = t - 17 + r;
                const unsigned int* row = xg + (120 + s) * N_;
                unsigned int sv[KPL];
                #pragma unroll
                for (int k = 0; k < KPL; ++k)          // coalesced cached reads
                    sv[k] = (wf[k] != 0.f) ? row[jj_[k]] : 0u;
                int g = 0;
                while (true) {                          // stale-SENT -> ALD retry
                    int pend = 0;
                    #pragma unroll
                    for (int k = 0; k < KPL; ++k) pend |= (sv[k] == SENT) ? 1 : 0;
                    if (!__any(pend)) break;
                    if (++g > 100000000) break;         // safety valve
                    #pragma unroll
                    for (int k = 0; k < KPL; ++k)
                        if (sv[k] == SENT) sv[k] = ALD(&row[jj_[k]]);
                }
                #pragma unroll
                for (int k = 0; k < KPL; ++k)
                    if (wf[k] != 0.f)
                        atomicAdd(&ring[wid][(s + df[k]) & 127],
                                  wf[k] * __uint_as_float(sv[k]));
            }
        }

        // ---- near poll (R0's proven elastic pattern) ----
        const int tb = t * N_;
        unsigned int vv[KPL];
        #pragma unroll
        for (int k = 0; k < KPL; ++k)
            vv[k] = (wn[k] != 0.f) ? ALD(&xg[an[k] + tb]) : 0u;
        int g = 0;
        while (true) {
            int pend = 0;
            #pragma unroll
            for (int k = 0; k < KPL; ++k) pend |= (vv[k] == SENT) ? 1 : 0;
            if (!__any(pend)) break;
            if (++g > 100000000) break;                 // safety valve
            #pragma unroll
            for (int k = 0; k < KPL; ++k)
                if (vv[k] == SENT) vv[k] = ALD(&xg[an[k] + tb]);
        }
        float acc = 0.f;
        #pragma unroll
        for (int k = 0; k < KPL; ++k) acc += wn[k] * __uint_as_float(vv[k]);
        #pragma unroll
        for (int o = 1; o < 64; o <<= 1) acc += __shfl_xor(acc, o, 64);

        float led = acc + ring[wid][t & 127];           // broadcast ds_read (uniform)
        if (lane == 0) ring[wid][t & 127] = 0.f;        // slot next written for t+128

        // ---- integrate / publish ----
        int tr = (t * 205) >> 11;                       // t/10 for t<400
        int sp = t - tr * 10;
        float u  = external[(i * SPT_ + sp) * TRS_ + tr];
        float n0 = noise[(t * N_ + i) * 2 + 0];
        float n1 = noise[(t * N_ + i) * 2 + 1];

        float r2 = x * x + y * y;
        float dx = (A_F - r2) * x - OMEGA_F * y + G_F * (led - rsum * x) + KGI_F * u;
        float dy = (A_F - r2) * y + OMEGA_F * x;
        x = x + DT_F * dx + n0;
        y = y + DT_F * dy + n1;

        if (lane == 0) {
            AST(&xg[(120 + t) * N_ + i], __float_as_uint(x));
            if (sp == SPT_ - 1) xtr[tr * N_ + i] = x;
        }
    }

    grid.sync();   // make xtr visible for the epilogue

    // epilogue: out[c*TRS + tr] = 5 * dot(xtr[tr,:], lm[c,:]) - 2
    for (int o = i; o < C_ * TRS_; o += 800) {
        int c = o / TRS_, tr = o - c * TRS_;
        float s = 0.f;
        #pragma unroll
        for (int k = 0; k < KPL; ++k) {
            int n = k * 64 + lane;
            if (n < N_) s += xtr[tr * N_ + n] * lm[c * N_ + n];
        }
        #pragma unroll
        for (int o2 = 1; o2 < 64; o2 <<= 1) s += __shfl_xor(s, o2, 64);
        if (lane == 0) out[o] = 5.0f * s - 2.0f;
    }
}

// ---------------- launch ----------------

extern "C" void kernel_launch(void* const* d_in, const int* in_sizes, int n_in,
                              void* d_out, int out_size, void* d_ws, size_t ws_size,
                              hipStream_t stream) {
    const float* external = (const float*)d_in[0];
    const float* hx       = (const float*)d_in[1];
    const float* hE       = (const float*)d_in[2];
    const float* sc       = (const float*)d_in[3];
    const float* lm       = (const float*)d_in[4];
    const float* noise    = (const float*)d_in[5];
    const int*   delays   = (const int*)  d_in[6];
    float* out = (float*)d_out;

    float*        sumsq = (float*)d_ws;                    // ws[0]
    int*          flag  = (int*)d_ws + 1;                  // ws[1]
    unsigned int* xg    = (unsigned int*)d_ws + 64;        // 520*800 words, time-major
    float*        xtr   = (float*)(xg + HIST_ * N_);       // 40*800 floats

    hipMemsetAsync(d_ws, 0, 8, stream);
    k_sumsq<<<256, 256, 0, stream>>>(sc, sumsq);
    k_detect<<<1, 256, 0, stream>>>(delays, flag);
    k_init<<<(HIST_ * N_ + 255) / 256, 256, 0, stream>>>(hE, xg);

    void* args[] = { (void*)&sc, (void*)&delays, (void*)&hx, (void*)&external,
                     (void*)&noise, (void*)&lm, (void*)&sumsq, (void*)&flag,
                     (void*)&xg, (void*)&xtr, (void*)&out };
    hipLaunchCooperativeKernel((const void*)k_main, dim3(100), dim3(512), args, 0, stream);
}